// Round 13
// baseline (279.951 us; speedup 1.0000x reference)
//
#include <hip/hip_runtime.h>
#include <math.h>

// Heat equation, temporally blocked. Round 13: K=24 steps/launch (11
// dispatches) + 4-ROW REGISTER BANDS: each thread owns 4 vertically
// stacked quads; inner vertical neighbors come from the unit's center
// registers, so per step per unit = 2 ds_read_b128 + 8 b32 + 4 b128w
// (29.6 cy/quad vs 47.6 scalar) -> DS-pipe issue 0.59us/step < 0.66us
// write stream -> steps are write-bound again at the deeper K.
// Tile 112x112 (stride 112), halo 24, double buffered 100.4 KB, 1024
// threads (784 active units, 1 unit/thread), shrinking validity window
// with per-row retire guards, inline register->global frame stores,
// barriers drain lgkmcnt only. Init folded into dispatch 0.

#define CORE 64
#define HALO 24
#define TILE 112           // tile side AND LDS row stride
#define TPB  1024
#define NQ   28            // float4 quads per tile row
#define NBANDS 28          // bands of 4 rows starting at row 1 (last partial)
#define NUNITS (NBANDS * NQ)   // 784

#define BAR() do { \
    asm volatile("s_waitcnt lgkmcnt(0)" ::: "memory"); \
    __builtin_amdgcn_s_barrier(); \
    __builtin_amdgcn_sched_barrier(0); \
} while (0)

// strict-interior load: element taken only if strictly inside the domain.
// Valid for u0 AND frames (frames carry zero boundaries).
__device__ __forceinline__ float4 load_quad_strict(const float* __restrict__ fp,
                                                   int gr, int gc0, int nX) {
    float4 v = make_float4(0.f, 0.f, 0.f, 0.f);
    if (gr > 0 && gr < nX - 1) {
        const float* sp = fp + (size_t)gr * nX + gc0;
        if (gc0 > 0 && gc0 + 3 < nX - 1) {
            v = *reinterpret_cast<const float4*>(sp);
        } else {
            if (gc0     > 0 && gc0     < nX - 1) v.x = sp[0];
            if (gc0 + 1 > 0 && gc0 + 1 < nX - 1) v.y = sp[1];
            if (gc0 + 2 > 0 && gc0 + 2 < nX - 1) v.z = sp[2];
            if (gc0 + 3 > 0 && gc0 + 3 < nX - 1) v.w = sp[3];
        }
    }
    return v;
}

__device__ __forceinline__ float4 mask_of(int gr, int gc0, int nX) {
    float4 m;
    const bool rin = (gr > 0 && gr < nX - 1);
    m.x = (rin && gc0     > 0 && gc0     < nX - 1) ? 1.f : 0.f;
    m.y = (rin && gc0 + 1 > 0 && gc0 + 1 < nX - 1) ? 1.f : 0.f;
    m.z = (rin && gc0 + 2 > 0 && gc0 + 2 < nX - 1) ? 1.f : 0.f;
    m.w = (rin && gc0 + 3 > 0 && gc0 + 3 < nX - 1) ? 1.f : 0.f;
    return m;
}

// one stencil quad: center c, vertical neighbors up/dn, scalar lf/rt
__device__ __forceinline__ float4 stencil(const float4& c, const float4& up,
                                          const float4& dn, float lf, float rt,
                                          const float4& m, float gamma) {
    float4 o;
    o.x = m.x * (c.x + gamma * (up.x + dn.x + lf  + c.y - 4.f * c.x));
    o.y = m.y * (c.y + gamma * (up.y + dn.y + c.x + c.z - 4.f * c.y));
    o.z = m.z * (c.z + gamma * (up.z + dn.z + c.y + c.w - 4.f * c.z));
    o.w = m.w * (c.w + gamma * (up.w + dn.w + c.z + rt  - 4.f * c.w));
    return o;
}

__global__ __launch_bounds__(TPB)
void heat_fused(const float* __restrict__ src,       // u0 (first) or frame t_base
                float* __restrict__ out,             // full output base
                int t_base, int k, int nX, int first,
                int time_steps,
                const float* __restrict__ alpha_p,
                const int* __restrict__ T_p) {
    __shared__ float buf[2][TILE * TILE];

    const int tid = threadIdx.x;
    const int gb  = nX / CORE;                 // 16
    const int bx  = blockIdx.x % gb;
    const int by  = blockIdx.x / gb;
    const int o_r = by * CORE - HALO;
    const int o_c = bx * CORE - HALO;
    const size_t n0 = (size_t)nX * nX;

    const float alpha = *alpha_p;
    const float Tf    = (float)(*T_p);
    const float dx    = 6.0f / (float)(nX - 1);
    const float dt    = Tf / (float)(time_steps - 1);
    const float gamma = alpha * dt / (dx * dx);

    // ---- load 112x112 tile (strict interior). first==1: store frame 0.
    for (int qi = tid; qi < TILE * NQ; qi += TPB) {
        const int r = qi / NQ, q = qi % NQ;
        const int gr = o_r + r, gc0 = o_c + 4 * q;
        const float4 v = load_quad_strict(src, gr, gc0, nX);
        *reinterpret_cast<float4*>(&buf[0][r * TILE + 4 * q]) = v;
        if (first && r >= HALO && r < HALO + CORE &&
            q >= HALO / 4 && q < (TILE - HALO) / 4)
            *reinterpret_cast<float4*>(out + (size_t)gr * nX + gc0) = v; // frame 0
    }
    BAR();

    // ---- unit invariants: band of rows r0..r0+3, one column quad ----
    const bool hasU = tid < NUNITS;
    const int band = tid / NQ;                 // 0..27
    const int q    = tid % NQ;                 // 0..27
    const int r0   = 1 + 4 * band;             // 1,5,...,109
    const int a0   = r0 * TILE + 4 * q;
    const int gc0  = o_c + 4 * q;
    const int off  = (o_r + r0) * nX + gc0;
    const bool qc  = (q >= HALO / 4 && q < (TILE - HALO) / 4);
    const int colm = min(4 * q + 2, 110 - 4 * q);

    int  mg[4];  bool st[4];  float4 m[4];
    #pragma unroll
    for (int i = 0; i < 4; ++i) {
        const int rr = r0 + i;                 // up to 112 (guarded by mg)
        mg[i] = hasU ? min(min(rr - 1, 110 - rr), colm) : -1;
        st[i] = (rr >= HALO && rr < HALO + CORE && qc);
        m[i]  = mask_of(o_r + rr, gc0, nX);
    }
    const int mgU = max(max(mg[0], mg[1]), max(mg[2], mg[3]));

    float4 c0, c1, c2, c3;
    const float4 z4 = make_float4(0.f, 0.f, 0.f, 0.f);
    c0 = (mg[0] >= 0) ? *reinterpret_cast<const float4*>(&buf[0][a0])            : z4;
    c1 = (mg[1] >= 0) ? *reinterpret_cast<const float4*>(&buf[0][a0 + TILE])     : z4;
    c2 = (mg[2] >= 0) ? *reinterpret_cast<const float4*>(&buf[0][a0 + 2 * TILE]) : z4;
    c3 = (mg[3] >= 0) ? *reinterpret_cast<const float4*>(&buf[0][a0 + 3 * TILE]) : z4;

    for (int s = 0; s < k; ++s) {
        const float* __restrict__ bc = buf[s & 1];
        float*       __restrict__ bn = buf[(s & 1) ^ 1];
        float* of = out + (size_t)(t_base + s + 1) * n0;

        if (s <= mgU) {
            const float4 oc0 = c0, oc1 = c1, oc2 = c2, oc3 = c3;
            if (s <= mg[0]) {
                const float4 u4 = *reinterpret_cast<const float4*>(bc + a0 - TILE);
                const float4 o = stencil(oc0, u4, oc1, bc[a0 - 1], bc[a0 + 4],
                                         m[0], gamma);
                *reinterpret_cast<float4*>(bn + a0) = o;
                if (st[0]) *reinterpret_cast<float4*>(of + off) = o;
                c0 = o;
            }
            if (s <= mg[1]) {
                const int a = a0 + TILE;
                const float4 o = stencil(oc1, oc0, oc2, bc[a - 1], bc[a + 4],
                                         m[1], gamma);
                *reinterpret_cast<float4*>(bn + a) = o;
                if (st[1]) *reinterpret_cast<float4*>(of + off + nX) = o;
                c1 = o;
            }
            if (s <= mg[2]) {
                const int a = a0 + 2 * TILE;
                const float4 o = stencil(oc2, oc1, oc3, bc[a - 1], bc[a + 4],
                                         m[2], gamma);
                *reinterpret_cast<float4*>(bn + a) = o;
                if (st[2]) *reinterpret_cast<float4*>(of + off + 2 * nX) = o;
                c2 = o;
            }
            if (s <= mg[3]) {
                const int a = a0 + 3 * TILE;
                const float4 d4 = *reinterpret_cast<const float4*>(bc + a + TILE);
                const float4 o = stencil(oc3, oc2, d4, bc[a - 1], bc[a + 4],
                                         m[3], gamma);
                *reinterpret_cast<float4*>(bn + a) = o;
                if (st[3]) *reinterpret_cast<float4*>(of + off + 3 * nX) = o;
                c3 = o;
            }
        }
        // LDS-only drain; global stores remain in flight across the barrier
        BAR();
    }
}

extern "C" void kernel_launch(void* const* d_in, const int* in_sizes, int n_in,
                              void* d_out, int out_size, void* d_ws, size_t ws_size,
                              hipStream_t stream) {
    const float* u0      = (const float*)d_in[0];
    const float* alpha_p = (const float*)d_in[1];
    const int*   T_p     = (const int*)d_in[2];

    const int n0 = in_sizes[0];                   // nX*nX
    const int nX = (int)(sqrtf((float)n0) + 0.5f);
    const int ts = out_size / n0;                 // time_steps

    float* out = (float*)d_out;
    const int gb = nX / CORE;                     // 16
    const int nblocks = gb * gb;                  // 256 = 1 block/CU

    for (int t = 0; t < ts - 1; t += HALO) {
        const int k = min(HALO, ts - 1 - t);
        const float* src = (t == 0) ? u0 : out + (size_t)t * n0;
        heat_fused<<<nblocks, TPB, 0, stream>>>(src, out, t, k, nX,
                                                (t == 0) ? 1 : 0, ts,
                                                alpha_p, T_p);
    }
}